// Round 8
// baseline (250.342 us; speedup 1.0000x reference)
//
#include <hip/hip_runtime.h>
#include <hip/hip_bf16.h>

// AttentionMixerRec: B=256 S=200 D=256 V=100000 L=5 H=4
// scores[b,h,l,s] = (ql[b,l] @ U[h]) . emb[b,s] / 16
//   U[h] = WQ[h]^T WK[h];  ql[b,l] = qpre[b,l] @ lin[l]^T;
//   qpre[b,l] = sum of emb rows s in [max(len-1-l,0), len-1].
// v8: chain fused into ONE 256-block kernel (1 block/CU -> all resident ->
//     flag-spin is deadlock-free by construction). Stage handoff = device-
//     scope flag flip instead of kernel drain + relaunch (was ~40us of
//     non-arithmetic time across 4 launches). GEMM tiles + attn = v7 verbatim.

#define DD 256
#define SS 200
#define BB 256
#define LL 5
#define HH 4
#define NC 20   // H*L
#define P_ER 264   // er pitch in halves
#define P_QT 260   // qt pitch in floats

__device__ __forceinline__ float bflo(unsigned u) {
    union { unsigned i; float f; } c; c.i = u << 16; return c.f;
}
__device__ __forceinline__ float bfhi(unsigned u) {
    union { unsigned i; float f; } c; c.i = u & 0xffff0000u; return c.f;
}

// ---- all-LDS GEMM tile: C[i0..+63, j0..+63] = A.B, K=256, 256 threads ----
template<bool A_T, bool B_T>
__device__ __forceinline__ void gemm64(const float* __restrict__ A,
                                       const float* __restrict__ B,
                                       float* __restrict__ C,
                                       int tile) {
    __shared__ float As[32][68];
    __shared__ float Bs[32][68];
    int i0 = (tile >> 2) * 64, j0 = (tile & 3) * 64;
    int t = threadIdx.x;
    int tx = t & 15, ty = t >> 4;
    float acc[4][4] = {};
    for (int k0 = 0; k0 < DD; k0 += 32) {
        #pragma unroll
        for (int r = 0; r < 8; ++r) {
            int e = r * 256 + t;
            if (A_T) {
                int i = e >> 5, k = e & 31;
                As[k][i] = A[(size_t)(i0 + i) * DD + k0 + k];
            } else {
                int kk = e >> 6, ii = e & 63;
                As[kk][ii] = A[(size_t)(k0 + kk) * DD + i0 + ii];
            }
            if (B_T) {
                int j = e >> 5, k = e & 31;
                Bs[k][j] = B[(size_t)(j0 + j) * DD + k0 + k];
            } else {
                int kk = e >> 6, jj = e & 63;
                Bs[kk][jj] = B[(size_t)(k0 + kk) * DD + j0 + jj];
            }
        }
        __syncthreads();
        #pragma unroll
        for (int kk = 0; kk < 32; ++kk) {
            float4 av = *(const float4*)&As[kk][tx * 4];
            float4 bv = *(const float4*)&Bs[kk][ty * 4];
            float a[4] = {av.x, av.y, av.z, av.w};
            float b[4] = {bv.x, bv.y, bv.z, bv.w};
            #pragma unroll
            for (int p = 0; p < 4; ++p)
                #pragma unroll
                for (int q = 0; q < 4; ++q)
                    acc[p][q] += a[p] * b[q];
        }
        __syncthreads();
    }
    #pragma unroll
    for (int p = 0; p < 4; ++p) {
        float4 v = {acc[p][0], acc[p][1], acc[p][2], acc[p][3]};
        *(float4*)&C[(size_t)(i0 + tx * 4 + p) * DD + j0 + ty * 4] = v;
    }
}

// ---- flag helpers (device-scope, cross-XCD safe) ----
__device__ __forceinline__ void flag_release(unsigned* f) {
    __syncthreads();                    // all threads' stores drained to L2
    if (threadIdx.x == 0) {
        __threadfence();                // agent-scope writeback
        __hip_atomic_fetch_add(f, 1u, __ATOMIC_RELEASE, __HIP_MEMORY_SCOPE_AGENT);
    }
}
__device__ __forceinline__ void flag_wait(unsigned* f, unsigned tgt) {
    if (threadIdx.x == 0) {
        long guard = 0;
        while (__hip_atomic_load(f, __ATOMIC_ACQUIRE, __HIP_MEMORY_SCOPE_AGENT) < tgt) {
            __builtin_amdgcn_s_sleep(4);
            if (++guard > 4000000) break;   // escape hatch: fail, don't hang
        }
    }
    __syncthreads();
    __threadfence();                    // invalidate stale cache lines
}
__device__ __forceinline__ void flag_wait2(unsigned* f1, unsigned t1,
                                           unsigned* f2, unsigned t2) {
    if (threadIdx.x == 0) {
        long guard = 0;
        while (__hip_atomic_load(f1, __ATOMIC_ACQUIRE, __HIP_MEMORY_SCOPE_AGENT) < t1 ||
               __hip_atomic_load(f2, __ATOMIC_ACQUIRE, __HIP_MEMORY_SCOPE_AGENT) < t2) {
            __builtin_amdgcn_s_sleep(4);
            if (++guard > 4000000) break;
        }
    }
    __syncthreads();
    __threadfence();
}

// ---- fused chain: qpre (all) -> U (blk<64) || ql (64..143) -> Qt (all) ----
// 256 blocks = 1/CU: all resident, spin-waits deadlock-free by construction.
__global__ __launch_bounds__(256) void k_chain(const float* __restrict__ wq,
                                               const float* __restrict__ wk,
                                               const float* __restrict__ lin,
                                               const int* __restrict__ seq,
                                               const int* __restrict__ slen,
                                               const float* __restrict__ emb,
                                               float* __restrict__ U,
                                               float* __restrict__ qpre,
                                               float* __restrict__ ql,
                                               float* __restrict__ Qt,
                                               unsigned* __restrict__ flags) {
    int blk = blockIdx.x, t = threadIdx.x;

    // stage 0: qpre for b = blk  (flag0 target 256)
    {
        int len = slen[blk];
        float acc = 0.f;
        int prev = len;
        #pragma unroll
        for (int l = 0; l < LL; ++l) {
            int lo = max(len - 1 - l, 0);
            while (prev > lo) {
                --prev;
                acc += emb[(size_t)seq[blk * SS + prev] * DD + t];
            }
            qpre[(size_t)(l * BB + blk) * DD + t] = acc;   // [l][b][d]
        }
    }
    flag_release(&flags[0]);

    // stage 1: U tiles (blocks 0..63, flag1 tgt 64) / ql tiles (64..143, flag2 tgt 80)
    if (blk < 64) {
        int h = blk >> 4;
        gemm64<false, false>(wq + (size_t)h * 65536, wk + (size_t)h * 65536,
                             U + (size_t)h * 65536, blk & 15);
        flag_release(&flags[1]);
    } else if (blk < 144) {
        int z = blk - 64;          // ql[l][b][e] = sum_d qpre[l][b][d]*lin[l][e][d]
        int l = z >> 4;
        flag_wait(&flags[0], 256);
        gemm64<true, true>(qpre + (size_t)l * 65536, lin + (size_t)l * 65536,
                           ql + (size_t)l * 65536, z & 15);
        flag_release(&flags[2]);
    }

    // stage 2: Qt tiles; tile q: z=q>>4 (=h*5+l), sub=q&15
    flag_wait2(&flags[1], 64, &flags[2], 80);
    {
        int q = blk;
        int z = q >> 4, h = z / 5, l = z % 5;
        gemm64<true, false>(ql + (size_t)l * 65536, U + (size_t)h * 65536,
                            Qt + (size_t)z * 65536, q & 15);
    }
    if (blk >= 144 && blk < 208) {
        int q = blk + 112;          // tiles 256..319
        int z = q >> 4, h = z / 5, l = z % 5;
        gemm64<true, false>(ql + (size_t)l * 65536, U + (size_t)h * 65536,
                            Qt + (size_t)z * 65536, q & 15);
    }
}

// ---- fused attention v7 (unchanged) ----
__global__ __launch_bounds__(1024, 4) void k_attn_out(const int* __restrict__ seq,
                                                      const float* __restrict__ emb,
                                                      const float* __restrict__ Qt,
                                                      float* __restrict__ out) {
    __shared__ float smem[38992];     // 152.3 KB
    __shared__ float ssum[NC];
    float* qt = smem;                                 // [20][P_QT] f32
    unsigned short* er = (unsigned short*)(smem + 5200);  // [256][P_ER] bf16
    float* e      = smem + 5200;                      // overlay after phase A
    float* pooled = smem + 5200 + NC * 256;           // [256]
    float* par    = pooled + 256;                     // [4][256]

    int b = blockIdx.x, t = threadIdx.x;
    int lane = t & 63, wave = t >> 6;
    int sg = lane >> 2, dq = lane & 3;
    int sgg = wave & 3;
    int mg = __builtin_amdgcn_readfirstlane(wave >> 2);

    for (int r = wave; r < NC; r += 16) {
        float4 v = *(const float4*)&Qt[((size_t)r * BB + b) * DD + lane * 4];
        *(float4*)&qt[r * P_QT + lane * 4] = v;
    }
    for (int r = wave; r < SS; r += 16) {
        int row = __builtin_amdgcn_readfirstlane(seq[b * SS + r]);
        float4 v = *(const float4*)&emb[(size_t)row * DD + lane * 4];
        __hip_bfloat162 p0 = __float22bfloat162_rn(make_float2(v.x, v.y));
        __hip_bfloat162 p1 = __float22bfloat162_rn(make_float2(v.z, v.w));
        union { __hip_bfloat162 h; unsigned u; } c0, c1;
        c0.h = p0; c1.h = p1;
        *(uint2*)&er[r * P_ER + lane * 4] = make_uint2(c0.u, c1.u);
    }
    __syncthreads();

    float acc[4][5] = {};
    int rbase = sgg * 16 + sg;
    const unsigned short* er0 = er + rbase * P_ER;
    for (int dj = 0; dj < 8; ++dj) {
        int rd = (dj + dq) & 7;
        int dcol = dq * 64 + rd * 8;
        float ev[4][8];
        #pragma unroll
        for (int j = 0; j < 4; ++j) {
            uint4 pv = *(const uint4*)&er0[j * 64 * P_ER + dcol];
            ev[j][0] = bflo(pv.x); ev[j][1] = bfhi(pv.x);
            ev[j][2] = bflo(pv.y); ev[j][3] = bfhi(pv.y);
            ev[j][4] = bflo(pv.z); ev[j][5] = bfhi(pv.z);
            ev[j][6] = bflo(pv.w); ev[j][7] = bfhi(pv.w);
        }
        #pragma unroll
        for (int mm = 0; mm < 5; ++mm) {
            const float* qm = &qt[(mg * 5 + mm) * P_QT + dcol];
            float4 q0 = *(const float4*)qm;
            float4 q1 = *(const float4*)(qm + 4);
            #pragma unroll
            for (int j = 0; j < 4; ++j) {
                float a = acc[j][mm];
                a = fmaf(ev[j][0], q0.x, a);
                a = fmaf(ev[j][1], q0.y, a);
                a = fmaf(ev[j][2], q0.z, a);
                a = fmaf(ev[j][3], q0.w, a);
                a = fmaf(ev[j][4], q1.x, a);
                a = fmaf(ev[j][5], q1.y, a);
                a = fmaf(ev[j][6], q1.z, a);
                a = fmaf(ev[j][7], q1.w, a);
                acc[j][mm] = a;
            }
        }
    }
    __syncthreads();

    #pragma unroll
    for (int j = 0; j < 4; ++j) {
        #pragma unroll
        for (int mm = 0; mm < 5; ++mm) {
            float v = acc[j][mm];
            v += __shfl_xor(v, 1);
            v += __shfl_xor(v, 2);
            if (dq == 0) {
                int s = rbase + 64 * j;
                e[(mg * 5 + mm) * 256 + s] = (s < SS) ? __expf(v * 0.0625f) : 0.f;
            }
        }
    }
    __syncthreads();

    for (int m = wave; m < NC; m += 16) {
        float v = e[m * 256 + lane] + e[m * 256 + lane + 64] +
                  e[m * 256 + lane + 128] + e[m * 256 + lane + 192];
        #pragma unroll
        for (int off = 32; off >= 1; off >>= 1) v += __shfl_xor(v, off);
        if (lane == 0) ssum[m] = __frcp_rn(v);
    }
    __syncthreads();

    if (t < 256) {
        float r = 0.f;
        #pragma unroll
        for (int h = 0; h < HH; ++h) {
            float p4 = 0.f;
            #pragma unroll
            for (int l = 0; l < LL; ++l) {
                int m = h * LL + l;
                float a = e[m * 256 + t] * ssum[m];
                float a2 = a * a;
                p4 += a2 * a2;
            }
            r += sqrtf(sqrtf(p4));
        }
        pooled[t] = 0.25f * r;
    }
    __syncthreads();

    int d = t & 255, sq = t >> 8;
    float o = 0.f;
    for (int i = 0; i < 50; ++i) {
        int s2 = sq * 50 + i;
        int rw = __builtin_amdgcn_readfirstlane(seq[b * SS + s2]);
        o = fmaf(pooled[s2], emb[(size_t)rw * DD + d], o);
    }
    par[sq * 256 + d] = o;
    __syncthreads();
    if (t < 256) out[(size_t)b * DD + t] =
        par[t] + par[256 + t] + par[512 + t] + par[768 + t];
}

extern "C" void kernel_launch(void* const* d_in, const int* in_sizes, int n_in,
                              void* d_out, int out_size, void* d_ws, size_t ws_size,
                              hipStream_t stream) {
    const int* seq = (const int*)d_in[0];
    const int* slen = (const int*)d_in[1];
    const float* emb = (const float*)d_in[2];
    const float* lin = (const float*)d_in[3];
    const float* wq = (const float*)d_in[4];
    const float* wk = (const float*)d_in[5];
    float* out = (float*)d_out;
    float* ws = (float*)d_ws;

    float* U    = ws;                // H * D*D   = 262144 floats
    float* qpre = ws + 262144;       // [l][b][d] = 327680
    float* ql   = ws + 589824;       // [l][b][d] = 327680
    float* Qt   = ws + 917504;       // [m][b][d] = 1310720
    unsigned* flags = (unsigned*)(ws + 2228224);   // 3 stage counters

    hipMemsetAsync(flags, 0, 16, stream);
    k_chain<<<dim3(BB), dim3(256), 0, stream>>>(wq, wk, lin, seq, slen, emb,
                                                U, qpre, ql, Qt, flags);
    k_attn_out<<<dim3(BB), dim3(1024), 0, stream>>>(seq, emb, Qt, out);
}

// Round 9
// 94.302 us; speedup vs baseline: 2.6547x; 2.6547x over previous
//
#include <hip/hip_runtime.h>
#include <hip/hip_bf16.h>

// AttentionMixerRec: B=256 S=200 D=256 V=100000 L=5 H=4
// scores[b,h,l,s] = (ql[b,l] @ U[h]) . emb[b,s] / 16
//   U[h] = WQ[h]^T WK[h];  ql[b,l] = qpre[b,l] @ lin[l]^T;
//   qpre[b,l] = sum of emb rows s in [max(len-1-l,0), len-1].
// v9: v8/v3 PROVED device-side stage sync (coop grid.sync AND manual
//     flag-spin) costs 100+us on this chip -> reverted. Instead exploit that
//     qpre->ql and ql->Qt are block-local in b: 2 kernels, 1 boundary.
//     K1: U tiles (64 blk) || per-b qpre(LDS)+ql-GEMV (256 blk).
//     K2: per-b Qt-GEMV from L2-resident U fused into attn (qt -> LDS
//     directly); Qt/qpre never touch global. attn phases = v7 verbatim.

#define DD 256
#define SS 200
#define BB 256
#define LL 5
#define HH 4
#define NC 20   // H*L
#define P_ER 264   // er pitch in halves
#define P_QT 260   // qt pitch in floats

__device__ __forceinline__ float bflo(unsigned u) {
    union { unsigned i; float f; } c; c.i = u << 16; return c.f;
}
__device__ __forceinline__ float bfhi(unsigned u) {
    union { unsigned i; float f; } c; c.i = u & 0xffff0000u; return c.f;
}

// ---- all-LDS GEMM tile: C[i0..+63, j0..+63] = A.B, K=256, 256 threads ----
__device__ __forceinline__ void gemm64_atb(const float* __restrict__ A,
                                           const float* __restrict__ B,
                                           float* __restrict__ C,
                                           int tile) {
    __shared__ float As[32][68];
    __shared__ float Bs[32][68];
    int i0 = (tile >> 2) * 64, j0 = (tile & 3) * 64;
    int t = threadIdx.x;
    int tx = t & 15, ty = t >> 4;
    float acc[4][4] = {};
    for (int k0 = 0; k0 < DD; k0 += 32) {
        #pragma unroll
        for (int r = 0; r < 8; ++r) {
            int e = r * 256 + t;
            int kk = e >> 6, ii = e & 63;
            As[kk][ii] = A[(size_t)(k0 + kk) * DD + i0 + ii];
            Bs[kk][ii] = B[(size_t)(k0 + kk) * DD + j0 + ii];
        }
        __syncthreads();
        #pragma unroll
        for (int kk = 0; kk < 32; ++kk) {
            float4 av = *(const float4*)&As[kk][tx * 4];
            float4 bv = *(const float4*)&Bs[kk][ty * 4];
            float a[4] = {av.x, av.y, av.z, av.w};
            float b[4] = {bv.x, bv.y, bv.z, bv.w};
            #pragma unroll
            for (int p = 0; p < 4; ++p)
                #pragma unroll
                for (int q = 0; q < 4; ++q)
                    acc[p][q] += a[p] * b[q];
        }
        __syncthreads();
    }
    #pragma unroll
    for (int p = 0; p < 4; ++p) {
        float4 v = {acc[p][0], acc[p][1], acc[p][2], acc[p][3]};
        *(float4*)&C[(size_t)(i0 + tx * 4 + p) * DD + j0 + ty * 4] = v;
    }
}

// ---- K1: blocks 0..63 = U[h] tiles; 64..319 = per-b qpre + ql GEMV ----
__global__ __launch_bounds__(256) void k_pre(const float* __restrict__ wq,
                                             const float* __restrict__ wk,
                                             const float* __restrict__ lin,
                                             const int* __restrict__ seq,
                                             const int* __restrict__ slen,
                                             const float* __restrict__ emb,
                                             float* __restrict__ U,
                                             float* __restrict__ qlg) {
    int blk = blockIdx.x, t = threadIdx.x;
    if (blk < 64) {
        int h = blk >> 4;
        gemm64_atb(wq + (size_t)h * 65536, wk + (size_t)h * 65536,
                   U + (size_t)h * 65536, blk & 15);
        return;
    }
    int b = blk - 64;
    __shared__ float qp[LL * 260];     // [l][260]

    // qpre gather (thread = d)
    {
        int len = slen[b];
        float acc = 0.f;
        int prev = len;
        #pragma unroll
        for (int l = 0; l < LL; ++l) {
            int lo = max(len - 1 - l, 0);
            while (prev > lo) {
                --prev;
                acc += emb[(size_t)seq[b * SS + prev] * DD + t];
            }
            qp[l * 260 + t] = acc;
        }
    }
    __syncthreads();

    // ql[l][e] = sum_d qp[l][d] * lin[l][e][d]
    // wave wv handles e in [wv*64, wv*64+64); 16-lane groups: i=lane&15 covers
    // d = i*16..+16, q=lane>>4 selects one of 4 concurrent e-rows.
    int lane = t & 63, wv = t >> 6;
    int i = lane & 15, q = lane >> 4;
    #pragma unroll
    for (int l = 0; l < LL; ++l) {
        float4 a0 = *(const float4*)&qp[l * 260 + i * 16];
        float4 a1 = *(const float4*)&qp[l * 260 + i * 16 + 4];
        float4 a2 = *(const float4*)&qp[l * 260 + i * 16 + 8];
        float4 a3 = *(const float4*)&qp[l * 260 + i * 16 + 12];
        for (int c = 0; c < 16; ++c) {
            int e = wv * 64 + c * 4 + q;
            const float* lr = lin + (size_t)l * 65536 + (size_t)e * DD + i * 16;
            float4 b0 = *(const float4*)lr;
            float4 b1 = *(const float4*)(lr + 4);
            float4 b2 = *(const float4*)(lr + 8);
            float4 b3 = *(const float4*)(lr + 12);
            float d = a0.x * b0.x + a0.y * b0.y + a0.z * b0.z + a0.w * b0.w
                    + a1.x * b1.x + a1.y * b1.y + a1.z * b1.z + a1.w * b1.w
                    + a2.x * b2.x + a2.y * b2.y + a2.z * b2.z + a2.w * b2.w
                    + a3.x * b3.x + a3.y * b3.y + a3.z * b3.z + a3.w * b3.w;
            d += __shfl_xor(d, 1);
            d += __shfl_xor(d, 2);
            d += __shfl_xor(d, 4);
            d += __shfl_xor(d, 8);
            if (i == 0) qlg[(size_t)b * (LL * DD) + l * DD + e] = d;
        }
    }
}

// ---- K2: per-b Qt-GEMV (from U) + attention, fully fused ----
__global__ __launch_bounds__(1024, 4) void k_attn2(const int* __restrict__ seq,
                                                   const float* __restrict__ emb,
                                                   const float* __restrict__ U,
                                                   const float* __restrict__ qlg,
                                                   float* __restrict__ out) {
    __shared__ float smem[38992];     // 152.3 KB
    __shared__ float ssum[NC];
    float* qt = smem;                                 // [20][P_QT] f32
    float* qlds = smem + 5200;                        // [5][256] (dead before er)
    unsigned short* er = (unsigned short*)(smem + 5200);  // [256][P_ER] bf16
    float* e      = smem + 5200;                      // overlay after phase A
    float* pooled = smem + 5200 + NC * 256;
    float* par    = pooled + 256;

    int b = blockIdx.x, t = threadIdx.x;
    int lane = t & 63, wave = t >> 6;

    // load ql[b] (1280 floats, coalesced)
    qlds[t] = qlg[(size_t)b * 1280 + t];
    if (t < 256) qlds[1024 + t] = qlg[(size_t)b * 1280 + 1024 + t];
    __syncthreads();

    // Qt GEMV: thread (d'=t&255, h=t>>8): qa[l] = sum_e qlds[l][e]*U[h][e][d']
    int dp = t & 255;
    int hq = __builtin_amdgcn_readfirstlane(t >> 8);
    const float* Ub = U + (size_t)hq * 65536 + dp;
    float qa[5] = {};
    for (int e4 = 0; e4 < 64; ++e4) {
        float4 q0 = *(const float4*)&qlds[0 * 256 + e4 * 4];   // uniform -> broadcast
        float4 q1 = *(const float4*)&qlds[1 * 256 + e4 * 4];
        float4 q2 = *(const float4*)&qlds[2 * 256 + e4 * 4];
        float4 q3 = *(const float4*)&qlds[3 * 256 + e4 * 4];
        float4 q4 = *(const float4*)&qlds[4 * 256 + e4 * 4];
        float u0 = Ub[(size_t)(e4 * 4 + 0) * DD];
        float u1 = Ub[(size_t)(e4 * 4 + 1) * DD];
        float u2 = Ub[(size_t)(e4 * 4 + 2) * DD];
        float u3 = Ub[(size_t)(e4 * 4 + 3) * DD];
        qa[0] += q0.x * u0 + q0.y * u1 + q0.z * u2 + q0.w * u3;
        qa[1] += q1.x * u0 + q1.y * u1 + q1.z * u2 + q1.w * u3;
        qa[2] += q2.x * u0 + q2.y * u1 + q2.z * u2 + q2.w * u3;
        qa[3] += q3.x * u0 + q3.y * u1 + q3.z * u2 + q3.w * u3;
        qa[4] += q4.x * u0 + q4.y * u1 + q4.z * u2 + q4.w * u3;
    }
    __syncthreads();   // all qlds reads done; er may overwrite
    #pragma unroll
    for (int l = 0; l < LL; ++l) qt[(hq * 5 + l) * P_QT + dp] = qa[l];

    // stage er: 200 emb rows as bf16
    for (int r = wave; r < SS; r += 16) {
        int row = __builtin_amdgcn_readfirstlane(seq[b * SS + r]);
        float4 v = *(const float4*)&emb[(size_t)row * DD + lane * 4];
        __hip_bfloat162 p0 = __float22bfloat162_rn(make_float2(v.x, v.y));
        __hip_bfloat162 p1 = __float22bfloat162_rn(make_float2(v.z, v.w));
        union { __hip_bfloat162 h; unsigned u; } c0, c1;
        c0.h = p0; c1.h = p1;
        *(uint2*)&er[r * P_ER + lane * 4] = make_uint2(c0.u, c1.u);
    }
    __syncthreads();

    // phase A (v7): thread = (sg,dq,sgg,mg); 4 s-rows x 5 m x 64 d
    int sg = lane >> 2, dq = lane & 3;
    int sgg = wave & 3;
    int mg = __builtin_amdgcn_readfirstlane(wave >> 2);
    float acc[4][5] = {};
    int rbase = sgg * 16 + sg;
    const unsigned short* er0 = er + rbase * P_ER;
    for (int dj = 0; dj < 8; ++dj) {
        int rd = (dj + dq) & 7;
        int dcol = dq * 64 + rd * 8;
        float ev[4][8];
        #pragma unroll
        for (int j = 0; j < 4; ++j) {
            uint4 pv = *(const uint4*)&er0[j * 64 * P_ER + dcol];
            ev[j][0] = bflo(pv.x); ev[j][1] = bfhi(pv.x);
            ev[j][2] = bflo(pv.y); ev[j][3] = bfhi(pv.y);
            ev[j][4] = bflo(pv.z); ev[j][5] = bfhi(pv.z);
            ev[j][6] = bflo(pv.w); ev[j][7] = bfhi(pv.w);
        }
        #pragma unroll
        for (int mm = 0; mm < 5; ++mm) {
            const float* qm = &qt[(mg * 5 + mm) * P_QT + dcol];
            float4 q0 = *(const float4*)qm;
            float4 q1 = *(const float4*)(qm + 4);
            #pragma unroll
            for (int j = 0; j < 4; ++j) {
                float a = acc[j][mm];
                a = fmaf(ev[j][0], q0.x, a);
                a = fmaf(ev[j][1], q0.y, a);
                a = fmaf(ev[j][2], q0.z, a);
                a = fmaf(ev[j][3], q0.w, a);
                a = fmaf(ev[j][4], q1.x, a);
                a = fmaf(ev[j][5], q1.y, a);
                a = fmaf(ev[j][6], q1.z, a);
                a = fmaf(ev[j][7], q1.w, a);
                acc[j][mm] = a;
            }
        }
    }
    __syncthreads();   // er dead; e/pooled/par overlay safe

    #pragma unroll
    for (int j = 0; j < 4; ++j) {
        #pragma unroll
        for (int mm = 0; mm < 5; ++mm) {
            float v = acc[j][mm];
            v += __shfl_xor(v, 1);
            v += __shfl_xor(v, 2);
            if (dq == 0) {
                int s = rbase + 64 * j;
                e[(mg * 5 + mm) * 256 + s] = (s < SS) ? __expf(v * 0.0625f) : 0.f;
            }
        }
    }
    __syncthreads();

    for (int m = wave; m < NC; m += 16) {
        float v = e[m * 256 + lane] + e[m * 256 + lane + 64] +
                  e[m * 256 + lane + 128] + e[m * 256 + lane + 192];
        #pragma unroll
        for (int off = 32; off >= 1; off >>= 1) v += __shfl_xor(v, off);
        if (lane == 0) ssum[m] = __frcp_rn(v);
    }
    __syncthreads();

    if (t < 256) {
        float r = 0.f;
        #pragma unroll
        for (int h = 0; h < HH; ++h) {
            float p4 = 0.f;
            #pragma unroll
            for (int l = 0; l < LL; ++l) {
                int m = h * LL + l;
                float a = e[m * 256 + t] * ssum[m];
                float a2 = a * a;
                p4 += a2 * a2;
            }
            r += sqrtf(sqrtf(p4));
        }
        pooled[t] = 0.25f * r;
    }
    __syncthreads();

    int d = t & 255, sq = t >> 8;
    float o = 0.f;
    for (int i2 = 0; i2 < 50; ++i2) {
        int s2 = sq * 50 + i2;
        int rw = __builtin_amdgcn_readfirstlane(seq[b * SS + s2]);
        o = fmaf(pooled[s2], emb[(size_t)rw * DD + d], o);
    }
    par[sq * 256 + d] = o;
    __syncthreads();
    if (t < 256) out[(size_t)b * DD + t] =
        par[t] + par[256 + t] + par[512 + t] + par[768 + t];
}

extern "C" void kernel_launch(void* const* d_in, const int* in_sizes, int n_in,
                              void* d_out, int out_size, void* d_ws, size_t ws_size,
                              hipStream_t stream) {
    const int* seq = (const int*)d_in[0];
    const int* slen = (const int*)d_in[1];
    const float* emb = (const float*)d_in[2];
    const float* lin = (const float*)d_in[3];
    const float* wq = (const float*)d_in[4];
    const float* wk = (const float*)d_in[5];
    float* out = (float*)d_out;
    float* ws = (float*)d_ws;

    float* U   = ws;                 // H * D*D   = 262144 floats
    float* qlg = ws + 262144;        // [b][l][e] = 327680 floats
    // total 2.36 MB workspace

    k_pre<<<dim3(320), dim3(256), 0, stream>>>(wq, wk, lin, seq, slen, emb, U, qlg);
    k_attn2<<<dim3(BB), dim3(1024), 0, stream>>>(seq, emb, U, qlg, out);
}

// Round 10
// 62.041 us; speedup vs baseline: 4.0351x; 1.5200x over previous
//
#include <hip/hip_runtime.h>
#include <hip/hip_bf16.h>

// AttentionMixerRec: B=256 S=200 D=256 V=100000 L=5 H=4
// scores[b,h,l,s] = (ql[b,l] @ U[h]) . emb[b,s] / 16
//   U[h] = WQ[h]^T WK[h];  ql[b,l] = qpre[b,l] @ lin[l]^T;
//   qpre[b,l] = sum of emb rows s in [max(len-1-l,0), len-1].
// v10: v9 proved per-b GEMV fusion is traffic-quadratic (each block re-reads
//     the full weight matrix; 256MB+ L2/L3) -> back to v7's GEMM-form chain.
//     New: k_Qt (336M MAC, ~20us fp32-LDS-bound) -> bf16 MFMA (16x16x32),
//     fed by k_wu epilogues emitting UT_bf (transposed bf16) and ql_bf.
//     bf16 touches only the score path (scores ~1e-5 -> error ~1e-8 at out).
//     k_qpre + attn = v7 verbatim.

#define DD 256
#define SS 200
#define BB 256
#define LL 5
#define HH 4
#define NC 20   // H*L
#define P_ER 264   // er pitch in halves
#define P_QT 260   // qt pitch in floats
#define P_BF 264   // bf16 slab pitch in k_qt (2-way bank alias = free)

typedef __attribute__((ext_vector_type(8))) short bf16x8;
typedef __attribute__((ext_vector_type(4))) float f32x4;

__device__ __forceinline__ float bflo(unsigned u) {
    union { unsigned i; float f; } c; c.i = u << 16; return c.f;
}
__device__ __forceinline__ float bfhi(unsigned u) {
    union { unsigned i; float f; } c; c.i = u & 0xffff0000u; return c.f;
}
__device__ __forceinline__ unsigned short f2bf(float f) {
    __hip_bfloat16 h = __float2bfloat16(f);
    union { __hip_bfloat16 b; unsigned short u; } c; c.b = h; return c.u;
}

// ---- all-LDS fp32 GEMM tile with bf16 epilogues ----
// C[i,j], i0/j0 from tile. EPI 0: O[j][i]=bf(C) (transposed, U path)
//                          EPI 1: O[i][j]=bf(C) (ql path). O row-stride 256.
template<bool A_T, bool B_T, int EPI>
__device__ __forceinline__ void gemm64e(const float* __restrict__ A,
                                        const float* __restrict__ B,
                                        unsigned short* __restrict__ O,
                                        int obase_row, int tile) {
    __shared__ float As[32][68];
    __shared__ float Bs[32][68];
    int i0 = (tile >> 2) * 64, j0 = (tile & 3) * 64;
    int t = threadIdx.x;
    int tx = t & 15, ty = t >> 4;
    float acc[4][4] = {};
    for (int k0 = 0; k0 < DD; k0 += 32) {
        #pragma unroll
        for (int r = 0; r < 8; ++r) {
            int e = r * 256 + t;
            if (A_T) {
                int i = e >> 5, k = e & 31;
                As[k][i] = A[(size_t)(i0 + i) * DD + k0 + k];
            } else {
                int kk = e >> 6, ii = e & 63;
                As[kk][ii] = A[(size_t)(k0 + kk) * DD + i0 + ii];
            }
            if (B_T) {
                int j = e >> 5, k = e & 31;
                Bs[k][j] = B[(size_t)(j0 + j) * DD + k0 + k];
            } else {
                int kk = e >> 6, jj = e & 63;
                Bs[kk][jj] = B[(size_t)(k0 + kk) * DD + j0 + jj];
            }
        }
        __syncthreads();
        #pragma unroll
        for (int kk = 0; kk < 32; ++kk) {
            float4 av = *(const float4*)&As[kk][tx * 4];
            float4 bv = *(const float4*)&Bs[kk][ty * 4];
            float a[4] = {av.x, av.y, av.z, av.w};
            float b[4] = {bv.x, bv.y, bv.z, bv.w};
            #pragma unroll
            for (int p = 0; p < 4; ++p)
                #pragma unroll
                for (int q = 0; q < 4; ++q)
                    acc[p][q] += a[p] * b[q];
        }
        __syncthreads();
    }
    if (EPI == 0) {
        #pragma unroll
        for (int q = 0; q < 4; ++q) {
            ushort4 v;
            v.x = f2bf(acc[0][q]); v.y = f2bf(acc[1][q]);
            v.z = f2bf(acc[2][q]); v.w = f2bf(acc[3][q]);
            *(ushort4*)&O[(size_t)(obase_row + j0 + ty * 4 + q) * DD + i0 + tx * 4] = v;
        }
    } else {
        #pragma unroll
        for (int p = 0; p < 4; ++p) {
            ushort4 v;
            v.x = f2bf(acc[p][0]); v.y = f2bf(acc[p][1]);
            v.z = f2bf(acc[p][2]); v.w = f2bf(acc[p][3]);
            *(ushort4*)&O[(size_t)(obase_row + i0 + tx * 4 + p) * DD + j0 + ty * 4] = v;
        }
    }
}

// ---- k_qpre: suffix-sum gather (256 blocks), fp32 [l][b][d] ----
__global__ __launch_bounds__(256) void k_qpre(const int* __restrict__ seq,
                                              const int* __restrict__ slen,
                                              const float* __restrict__ emb,
                                              float* __restrict__ qpre) {
    int b = blockIdx.x, t = threadIdx.x;
    int len = slen[b];
    float acc = 0.f;
    int prev = len;
    #pragma unroll
    for (int l = 0; l < LL; ++l) {
        int lo = max(len - 1 - l, 0);
        while (prev > lo) {
            --prev;
            acc += emb[(size_t)seq[b * SS + prev] * DD + t];
        }
        qpre[(size_t)(l * BB + b) * DD + t] = acc;
    }
}

// ---- k_wu: blocks 0..63 = U[h] -> UT_bf; blocks 64..143 = ql -> ql_bf ----
__global__ __launch_bounds__(256) void k_wu(const float* __restrict__ wq,
                                            const float* __restrict__ wk,
                                            const float* __restrict__ qpre,
                                            const float* __restrict__ lin,
                                            unsigned short* __restrict__ UT_bf,
                                            unsigned short* __restrict__ ql_bf) {
    int blk = blockIdx.x;
    if (blk < 64) {
        int h = blk >> 4;
        // C[i][j] = sum_k wq[k][i] wk[k][j] = U[i][j]; store UT_bf[h][j][i]
        gemm64e<false, false, 0>(wq + (size_t)h * 65536, wk + (size_t)h * 65536,
                                 UT_bf, h * 256, blk & 15);
    } else {
        int z = blk - 64;
        int l = z >> 4;
        // C[b][e] = sum_d qpre[l][b][d] lin[l][e][d]; store ql_bf[l][b][e]
        gemm64e<true, true, 1>(qpre + (size_t)l * 65536, lin + (size_t)l * 65536,
                               ql_bf, l * 256, z & 15);
    }
}

// ---- k_qt: Qt[z=h*5+l][b][d'] via bf16 MFMA, tile 128x64, 160 blocks ----
// A = ql_bf[l] (rows b, k=e contig); B = UT_bf[h] (rows d', k=e contig).
__global__ __launch_bounds__(256) void k_qt(const unsigned short* __restrict__ ql_bf,
                                            const unsigned short* __restrict__ UT_bf,
                                            float* __restrict__ Qt) {
    __shared__ unsigned short Asl[128 * P_BF];   // 67.6 KB
    __shared__ unsigned short Bsl[64 * P_BF];    // 33.8 KB
    int blk = blockIdx.x;
    int z = blk >> 3, sub = blk & 7;
    int h = z / 5, l = z % 5;
    int b0 = (sub >> 2) * 128, d0 = (sub & 3) * 64;
    int t = threadIdx.x, lane = t & 63, w = t >> 6;

    const unsigned short* gA = ql_bf + ((size_t)l * 256 + b0) * DD;
    #pragma unroll
    for (int r = 0; r < 16; ++r) {
        int c = r * 256 + t;            // 0..4095
        int row = c >> 5, kc = c & 31;
        *(uint4*)&Asl[row * P_BF + kc * 8] = *(const uint4*)&gA[(size_t)row * DD + kc * 8];
    }
    const unsigned short* gB = UT_bf + ((size_t)h * 256 + d0) * DD;
    #pragma unroll
    for (int r = 0; r < 8; ++r) {
        int c = r * 256 + t;            // 0..2047
        int row = c >> 5, kc = c & 31;
        *(uint4*)&Bsl[row * P_BF + kc * 8] = *(const uint4*)&gB[(size_t)row * DD + kc * 8];
    }
    __syncthreads();

    f32x4 zero = {0.f, 0.f, 0.f, 0.f};
    f32x4 acc[2][4];
    #pragma unroll
    for (int p = 0; p < 2; ++p)
        #pragma unroll
        for (int q = 0; q < 4; ++q) acc[p][q] = zero;

    int ar = w * 32 + (lane & 15);      // A frag row base (p*16 offset added)
    int br = lane & 15;                 // B frag row base (q*16 offset)
    int ko = (lane >> 4) * 8;           // per-lane k offset
    for (int kk = 0; kk < 8; ++kk) {
        int kb = kk * 32 + ko;
        bf16x8 a0 = *(const bf16x8*)&Asl[(size_t)ar * P_BF + kb];
        bf16x8 a1 = *(const bf16x8*)&Asl[(size_t)(ar + 16) * P_BF + kb];
        bf16x8 b0 = *(const bf16x8*)&Bsl[(size_t)br * P_BF + kb];
        bf16x8 b1 = *(const bf16x8*)&Bsl[(size_t)(br + 16) * P_BF + kb];
        bf16x8 b2 = *(const bf16x8*)&Bsl[(size_t)(br + 32) * P_BF + kb];
        bf16x8 b3 = *(const bf16x8*)&Bsl[(size_t)(br + 48) * P_BF + kb];
        acc[0][0] = __builtin_amdgcn_mfma_f32_16x16x32_bf16(a0, b0, acc[0][0], 0, 0, 0);
        acc[0][1] = __builtin_amdgcn_mfma_f32_16x16x32_bf16(a0, b1, acc[0][1], 0, 0, 0);
        acc[0][2] = __builtin_amdgcn_mfma_f32_16x16x32_bf16(a0, b2, acc[0][2], 0, 0, 0);
        acc[0][3] = __builtin_amdgcn_mfma_f32_16x16x32_bf16(a0, b3, acc[0][3], 0, 0, 0);
        acc[1][0] = __builtin_amdgcn_mfma_f32_16x16x32_bf16(a1, b0, acc[1][0], 0, 0, 0);
        acc[1][1] = __builtin_amdgcn_mfma_f32_16x16x32_bf16(a1, b1, acc[1][1], 0, 0, 0);
        acc[1][2] = __builtin_amdgcn_mfma_f32_16x16x32_bf16(a1, b2, acc[1][2], 0, 0, 0);
        acc[1][3] = __builtin_amdgcn_mfma_f32_16x16x32_bf16(a1, b3, acc[1][3], 0, 0, 0);
    }

    // D layout: row=(lane>>4)*4+j, col=lane&15  [guide m89-verified]
    int crow = (lane >> 4) * 4, ccol = lane & 15;
    float* Qb = Qt + (size_t)z * 65536;
    #pragma unroll
    for (int p = 0; p < 2; ++p)
        #pragma unroll
        for (int q = 0; q < 4; ++q)
            #pragma unroll
            for (int j = 0; j < 4; ++j) {
                int row = b0 + w * 32 + p * 16 + crow + j;
                int col = d0 + q * 16 + ccol;
                Qb[(size_t)row * DD + col] = acc[p][q][j];
            }
}

// ---- fused attention (v7 verbatim); Qt layout [m][b][d] ----
__global__ __launch_bounds__(1024, 4) void k_attn_out(const int* __restrict__ seq,
                                                      const float* __restrict__ emb,
                                                      const float* __restrict__ Qt,
                                                      float* __restrict__ out) {
    __shared__ float smem[38992];
    __shared__ float ssum[NC];
    float* qt = smem;                                 // [20][P_QT] f32
    unsigned short* er = (unsigned short*)(smem + 5200);  // [256][P_ER] bf16
    float* e      = smem + 5200;
    float* pooled = smem + 5200 + NC * 256;
    float* par    = pooled + 256;

    int b = blockIdx.x, t = threadIdx.x;
    int lane = t & 63, wave = t >> 6;
    int sg = lane >> 2, dq = lane & 3;
    int sgg = wave & 3;
    int mg = __builtin_amdgcn_readfirstlane(wave >> 2);

    for (int r = wave; r < NC; r += 16) {
        float4 v = *(const float4*)&Qt[((size_t)r * BB + b) * DD + lane * 4];
        *(float4*)&qt[r * P_QT + lane * 4] = v;
    }
    for (int r = wave; r < SS; r += 16) {
        int row = __builtin_amdgcn_readfirstlane(seq[b * SS + r]);
        float4 v = *(const float4*)&emb[(size_t)row * DD + lane * 4];
        __hip_bfloat162 p0 = __float22bfloat162_rn(make_float2(v.x, v.y));
        __hip_bfloat162 p1 = __float22bfloat162_rn(make_float2(v.z, v.w));
        union { __hip_bfloat162 h; unsigned u; } c0, c1;
        c0.h = p0; c1.h = p1;
        *(uint2*)&er[r * P_ER + lane * 4] = make_uint2(c0.u, c1.u);
    }
    __syncthreads();

    float acc[4][5] = {};
    int rbase = sgg * 16 + sg;
    const unsigned short* er0 = er + rbase * P_ER;
    for (int dj = 0; dj < 8; ++dj) {
        int rd = (dj + dq) & 7;
        int dcol = dq * 64 + rd * 8;
        float ev[4][8];
        #pragma unroll
        for (int j = 0; j < 4; ++j) {
            uint4 pv = *(const uint4*)&er0[j * 64 * P_ER + dcol];
            ev[j][0] = bflo(pv.x); ev[j][1] = bfhi(pv.x);
            ev[j][2] = bflo(pv.y); ev[j][3] = bfhi(pv.y);
            ev[j][4] = bflo(pv.z); ev[j][5] = bfhi(pv.z);
            ev[j][6] = bflo(pv.w); ev[j][7] = bfhi(pv.w);
        }
        #pragma unroll
        for (int mm = 0; mm < 5; ++mm) {
            const float* qm = &qt[(mg * 5 + mm) * P_QT + dcol];
            float4 q0 = *(const float4*)qm;
            float4 q1 = *(const float4*)(qm + 4);
            #pragma unroll
            for (int j = 0; j < 4; ++j) {
                float a = acc[j][mm];
                a = fmaf(ev[j][0], q0.x, a);
                a = fmaf(ev[j][1], q0.y, a);
                a = fmaf(ev[j][2], q0.z, a);
                a = fmaf(ev[j][3], q0.w, a);
                a = fmaf(ev[j][4], q1.x, a);
                a = fmaf(ev[j][5], q1.y, a);
                a = fmaf(ev[j][6], q1.z, a);
                a = fmaf(ev[j][7], q1.w, a);
                acc[j][mm] = a;
            }
        }
    }
    __syncthreads();

    #pragma unroll
    for (int j = 0; j < 4; ++j) {
        #pragma unroll
        for (int mm = 0; mm < 5; ++mm) {
            float v = acc[j][mm];
            v += __shfl_xor(v, 1);
            v += __shfl_xor(v, 2);
            if (dq == 0) {
                int s = rbase + 64 * j;
                e[(mg * 5 + mm) * 256 + s] = (s < SS) ? __expf(v * 0.0625f) : 0.f;
            }
        }
    }
    __syncthreads();

    for (int m = wave; m < NC; m += 16) {
        float v = e[m * 256 + lane] + e[m * 256 + lane + 64] +
                  e[m * 256 + lane + 128] + e[m * 256 + lane + 192];
        #pragma unroll
        for (int off = 32; off >= 1; off >>= 1) v += __shfl_xor(v, off);
        if (lane == 0) ssum[m] = __frcp_rn(v);
    }
    __syncthreads();

    if (t < 256) {
        float r = 0.f;
        #pragma unroll
        for (int h = 0; h < HH; ++h) {
            float p4 = 0.f;
            #pragma unroll
            for (int l = 0; l < LL; ++l) {
                int m = h * LL + l;
                float a = e[m * 256 + t] * ssum[m];
                float a2 = a * a;
                p4 += a2 * a2;
            }
            r += sqrtf(sqrtf(p4));
        }
        pooled[t] = 0.25f * r;
    }
    __syncthreads();

    int d = t & 255, sq = t >> 8;
    float o = 0.f;
    for (int i = 0; i < 50; ++i) {
        int s2 = sq * 50 + i;
        int rw = __builtin_amdgcn_readfirstlane(seq[b * SS + s2]);
        o = fmaf(pooled[s2], emb[(size_t)rw * DD + d], o);
    }
    par[sq * 256 + d] = o;
    __syncthreads();
    if (t < 256) out[(size_t)b * DD + t] =
        par[t] + par[256 + t] + par[512 + t] + par[768 + t];
}

extern "C" void kernel_launch(void* const* d_in, const int* in_sizes, int n_in,
                              void* d_out, int out_size, void* d_ws, size_t ws_size,
                              hipStream_t stream) {
    const int* seq = (const int*)d_in[0];
    const int* slen = (const int*)d_in[1];
    const float* emb = (const float*)d_in[2];
    const float* lin = (const float*)d_in[3];
    const float* wq = (const float*)d_in[4];
    const float* wk = (const float*)d_in[5];
    float* out = (float*)d_out;
    float* ws = (float*)d_ws;

    float* qpre = ws;                          // [l][b][d] fp32 = 327680 floats
    float* Qt   = ws + 327680;                 // [m][b][d] fp32 = 1310720
    unsigned short* UT_bf = (unsigned short*)(ws + 1638400);  // [h][d'][e] = 262144 us
    unsigned short* ql_bf = (unsigned short*)(ws + 1769472);  // [l][b][e] = 327680 us
    // ends at float offset 1933312 = 7.73 MB

    k_qpre<<<dim3(BB), dim3(256), 0, stream>>>(seq, slen, emb, qpre);
    k_wu<<<dim3(144), dim3(256), 0, stream>>>(wq, wk, qpre, lin, UT_bf, ql_bf);
    k_qt<<<dim3(160), dim3(256), 0, stream>>>(ql_bf, UT_bf, Qt);
    k_attn_out<<<dim3(BB), dim3(1024), 0, stream>>>(seq, emb, Qt, out);
}